// Round 5
// baseline (279.543 us; speedup 1.0000x reference)
//
#include <hip/hip_runtime.h>
#include <hip/hip_bf16.h>

typedef _Float16 half8v __attribute__((ext_vector_type(8)));
typedef __fp16  fp16x2 __attribute__((ext_vector_type(2)));   // cvt_pkrtz return type
typedef float floatx4 __attribute__((ext_vector_type(4)));

#define NB 32
#define NT 2048
#define ND 1024
#define NM (NB * NT)

// global->LDS direct DMA, 16B per lane. Linear LDS dest (wave-uniform base +
// lane*16); swizzle is applied on the GLOBAL source address (rule #21).
#define GL16(g, l)                                                             \
    __builtin_amdgcn_global_load_lds(                                          \
        (const __attribute__((address_space(1))) void*)(g),                    \
        (__attribute__((address_space(3))) void*)(l), 16, 0, 0)

__device__ __forceinline__ float fast_tanh(float x) {
    x = fminf(9.0f, fmaxf(-9.0f, x));
    float e = __builtin_amdgcn_exp2f(x * 2.8853900817779268f); // e^(2x)
    return (e - 1.0f) * __builtin_amdgcn_rcpf(e + 1.0f);
}

// ---------------- W [K][N] f32  ->  Wt [N][K] fp16 ----------------
__global__ __launch_bounds__(256)
void wt_kernel(const float* __restrict__ W, _Float16* __restrict__ Wt) {
    __shared__ float tile[32][33];
    int tx = threadIdx.x, ty = threadIdx.y;
    int bx = blockIdx.x, by = blockIdx.y;
    #pragma unroll
    for (int i = 0; i < 4; ++i) {
        int y = by * 32 + ty + i * 8;
        tile[ty + i * 8][tx] = W[y * ND + bx * 32 + tx];
    }
    __syncthreads();
    #pragma unroll
    for (int i = 0; i < 4; ++i) {
        int e = bx * 32 + ty + i * 8;
        Wt[e * ND + by * 32 + tx] = (_Float16)tile[tx][ty + i * 8];
    }
}

// ---------------- many f32 -> manyh fp16 (streaming, RTN) ----------------
__global__ __launch_bounds__(256)
void conv_kernel(const float* __restrict__ many, _Float16* __restrict__ manyh) {
    size_t idx = ((size_t)blockIdx.x * 256 + threadIdx.x) * 8;
    size_t stride = (size_t)gridDim.x * 256 * 8;
    for (size_t i = idx; i < (size_t)NM * ND; i += stride) {
        float4 a = *reinterpret_cast<const float4*>(many + i);
        float4 b = *reinterpret_cast<const float4*>(many + i + 4);
        union { _Float16 h[8]; uint4 u; } o;
        o.h[0] = (_Float16)a.x; o.h[1] = (_Float16)a.y;
        o.h[2] = (_Float16)a.z; o.h[3] = (_Float16)a.w;
        o.h[4] = (_Float16)b.x; o.h[5] = (_Float16)b.y;
        o.h[6] = (_Float16)b.z; o.h[7] = (_Float16)b.w;
        *reinterpret_cast<uint4*>(manyh + i) = o.u;
    }
}

// ------- 8-phase-style GEMM + tanh + dot(one) -> logits (fp16, 256x256) -----
// manyh [65536][1024] fp16, Wt [1024][1024] fp16, both K-contiguous.
// BM=BN=256, BK=32, 512 thr (8 waves 2Mx4N, wave=128x64). 4 LDS bufs x 32KB,
// prefetch depth 3 tiles, counted vmcnt(8) once per K-tile (never 0 in loop).
__global__ __launch_bounds__(512, 2)
void gemm_logits_8p(const _Float16* __restrict__ manyh, const _Float16* __restrict__ Wt,
                    const float* __restrict__ one, float* __restrict__ logits) {
    __shared__ uint4 LDSQ[8192];          // 128 KiB = 4 bufs x (A 16K | B 16K)
    char* Ld = (char*)LDSQ;

    int bid = blockIdx.x;                  // 1024 blocks
    int j = (bid & 7) * 128 + (bid >> 3);  // XCD-chunked (1024 % 8 == 0, bijective)
    int mb = j >> 2, nb = j & 3;
    int m0 = mb * 256, n0 = nb * 256;

    int tid = threadIdx.x;
    int lane = tid & 63, w = tid >> 6;
    int wr = w >> 2, wc = w & 3;          // 2 M-halves x 4 N-quarters
    int l15 = lane & 15, l4 = lane >> 4;

    // Staging: thread t stages 16B chunk: local row = t>>2 (0..127) (+q*128),
    // chunk cc = t&3, src chunk = cc ^ ((row>>1)&3)  (2-bit key: 4 chunks/row;
    // q*128 = 0 mod 4 so key is q-invariant). 2-way residual alias = free.
    const char* aS = (const char*)manyh + ((size_t)(m0 + (tid >> 2)) << 11)
                   + (size_t)(((tid & 3) ^ ((tid >> 3) & 3)) << 4);
    const char* bS = (const char*)Wt   + ((size_t)(n0 + (tid >> 2)) << 11)
                   + (size_t)(((tid & 3) ^ ((tid >> 3) & 3)) << 4);

    // QBASE: 0 = A halves (q0,q1), 2 = B halves (q2,q3); tile TP -> buf TP&3
#define STAGE2(QBASE, TP) do {                                                 \
        int nxt_ = ((TP) & 3) * 32768;                                         \
        int kn_ = (TP) * 64;                                                   \
        const char* s_ = (QBASE) < 2 ? aS : bS;                                \
        GL16(s_ + kn_,          Ld + nxt_ + (QBASE) * 8192 + tid * 16);        \
        GL16(s_ + 262144 + kn_, Ld + nxt_ + (QBASE) * 8192 + 8192 + tid * 16); \
    } while (0)

    floatx4 acc[8][4] = {};

    // prologue: tiles 0,1,2 fully issued (12 loads); wait tile0 (allow 8)
    #pragma unroll
    for (int pre = 0; pre < 3; ++pre) { STAGE2(0, pre); STAGE2(2, pre); }
    asm volatile("s_waitcnt vmcnt(8)" ::: "memory");
    __builtin_amdgcn_sched_barrier(0);
    __builtin_amdgcn_s_barrier();

    #pragma unroll 1
    for (int t = 0; t < 32; ++t) {
        int cur = (t & 3) * 32768;
        half8v af[4], bf[4];
        // -------- phase 0: M-half 0, load B frags (kept for phase 1) --------
        #pragma unroll
        for (int mi = 0; mi < 4; ++mi) {
            int r = wr * 128 + mi * 16 + l15;
            af[mi] = *(const half8v*)(Ld + cur + r * 64 + ((l4 ^ ((r >> 1) & 3)) << 4));
        }
        #pragma unroll
        for (int ni = 0; ni < 4; ++ni) {
            int r = wc * 64 + ni * 16 + l15;
            bf[ni] = *(const half8v*)(Ld + cur + 16384 + r * 64 + ((l4 ^ ((r >> 1) & 3)) << 4));
        }
        if (t < 29) STAGE2(0, t + 3);      // prefetch A of tile t+3
        __builtin_amdgcn_s_barrier();
        __builtin_amdgcn_s_setprio(1);
        #pragma unroll
        for (int mi = 0; mi < 4; ++mi)
            #pragma unroll
            for (int ni = 0; ni < 4; ++ni)
                acc[mi][ni] = __builtin_amdgcn_mfma_f32_16x16x32_f16(
                    af[mi], bf[ni], acc[mi][ni], 0, 0, 0);
        __builtin_amdgcn_s_setprio(0);
        __builtin_amdgcn_s_barrier();
        // -------- phase 1: M-half 1, reuse B frags --------
        #pragma unroll
        for (int mi = 0; mi < 4; ++mi) {
            int r = wr * 128 + 64 + mi * 16 + l15;
            af[mi] = *(const half8v*)(Ld + cur + r * 64 + ((l4 ^ ((r >> 1) & 3)) << 4));
        }
        if (t < 29) STAGE2(2, t + 3);      // prefetch B of tile t+3
        __builtin_amdgcn_s_barrier();
        __builtin_amdgcn_s_setprio(1);
        #pragma unroll
        for (int mi = 0; mi < 4; ++mi)
            #pragma unroll
            for (int ni = 0; ni < 4; ++ni)
                acc[4 + mi][ni] = __builtin_amdgcn_mfma_f32_16x16x32_f16(
                    af[mi], bf[ni], acc[4 + mi][ni], 0, 0, 0);
        __builtin_amdgcn_s_setprio(0);
        // tile-boundary wait: allow only loads newer than tile t+1
        if (t <= 28)      asm volatile("s_waitcnt vmcnt(8)" ::: "memory");
        else if (t == 29) asm volatile("s_waitcnt vmcnt(4)" ::: "memory");
        else if (t == 30) asm volatile("s_waitcnt vmcnt(0)" ::: "memory");
        __builtin_amdgcn_sched_barrier(0);
        __builtin_amdgcn_s_barrier();
    }
#undef STAGE2

    // epilogue: tanh * one, reduce over 16 col-lanes, atomicAdd logits
    int bidx = m0 >> 11;
    float onev[4];
    #pragma unroll
    for (int ni = 0; ni < 4; ++ni)
        onev[ni] = one[(bidx << 10) + n0 + wc * 64 + ni * 16 + l15];

    #pragma unroll
    for (int mi = 0; mi < 8; ++mi) {
        float part[4] = {0.f, 0.f, 0.f, 0.f};
        #pragma unroll
        for (int ni = 0; ni < 4; ++ni)
            #pragma unroll
            for (int b = 0; b < 4; ++b)
                part[b] += fast_tanh(acc[mi][ni][b]) * onev[ni];
        #pragma unroll
        for (int off = 1; off < 16; off <<= 1)
            #pragma unroll
            for (int b = 0; b < 4; ++b)
                part[b] += __shfl_xor(part[b], off, 64);
        #pragma unroll
        for (int b = 0; b < 4; ++b)
            if (l15 == ((mi * 4 + b) & 15))
                atomicAdd(&logits[m0 + wr * 128 + mi * 16 + l4 * 4 + b], part[b]);
    }
}

// ---------------- fallback GEMM (A f32 from global, cvt at frag read) ------
__global__ __launch_bounds__(256, 2)
void gemm_logits(const float* __restrict__ many, const _Float16* __restrict__ Wt,
                 const float* __restrict__ one, float* __restrict__ logits) {
    __shared__ uint4 AsQ[2048];
    __shared__ uint4 BsQ[1024];
    char* AsB = (char*)AsQ;
    char* BsB = (char*)BsQ;

    int bid = blockIdx.x;
    int j = (bid & 7) * 512 + (bid >> 3);
    int mb = j >> 3, nb = j & 7;
    int m0 = mb * 128, n0 = nb * 128;

    int tid = threadIdx.x;
    int lane = tid & 63, w = tid >> 6;
    int wr = w >> 1, wc = w & 1;
    int l15 = lane & 15, l4 = lane >> 4;

    const char* aS = (const char*)many + ((size_t)(m0 + (tid >> 4)) << 12)
        + (size_t)(((tid & 15) ^ ((tid >> 4) & 7)) << 4);
    const char* bS = (const char*)Wt + ((size_t)(n0 + (tid >> 3)) << 11)
        + (size_t)(((tid & 7) ^ ((tid >> 3) & 7)) << 4);
    char* aD = AsB + tid * 16;
    char* bD = BsB + tid * 16;

    floatx4 acc[4][4] = {};

    for (int kb = 0; kb < 1024; kb += 64) {
        #pragma unroll
        for (int i = 0; i < 8; ++i)
            GL16(aS + kb * 4 + i * 65536, aD + i * 4096);
        #pragma unroll
        for (int i = 0; i < 4; ++i)
            GL16(bS + kb * 2 + i * 65536, bD + i * 4096);
        __syncthreads();

        #pragma unroll
        for (int ks = 0; ks < 64; ks += 32) {
            half8v af[4], bf[4];
            #pragma unroll
            for (int mi = 0; mi < 4; ++mi) {
                int r = wr * 64 + mi * 16 + l15;
                int s = l15 & 7;
                const char* base = AsB + r * 256;
                int c0 = (ks >> 2) + l4 * 2;
                float4 x = *(const float4*)(base + (size_t)((c0 ^ s) << 4));
                float4 y = *(const float4*)(base + (size_t)(((c0 + 1) ^ s) << 4));
                union { fp16x2 p[4]; half8v h; } u;
                u.p[0] = __builtin_amdgcn_cvt_pkrtz(x.x, x.y);
                u.p[1] = __builtin_amdgcn_cvt_pkrtz(x.z, x.w);
                u.p[2] = __builtin_amdgcn_cvt_pkrtz(y.x, y.y);
                u.p[3] = __builtin_amdgcn_cvt_pkrtz(y.z, y.w);
                af[mi] = u.h;
            }
            #pragma unroll
            for (int ni = 0; ni < 4; ++ni) {
                int r = wc * 64 + ni * 16 + l15;
                int s = l15 & 7;
                int c = (ks >> 3) + l4;
                bf[ni] = *(const half8v*)(BsB + r * 128 + (size_t)((c ^ s) << 4));
            }
            #pragma unroll
            for (int mi = 0; mi < 4; ++mi)
                #pragma unroll
                for (int ni = 0; ni < 4; ++ni)
                    acc[mi][ni] = __builtin_amdgcn_mfma_f32_16x16x32_f16(
                        af[mi], bf[ni], acc[mi][ni], 0, 0, 0);
        }
        __syncthreads();
    }

    int bidx = m0 >> 11;
    float onev[4];
    #pragma unroll
    for (int ni = 0; ni < 4; ++ni)
        onev[ni] = one[(bidx << 10) + n0 + wc * 64 + ni * 16 + l15];

    #pragma unroll
    for (int mi = 0; mi < 4; ++mi) {
        float part[4] = {0.f, 0.f, 0.f, 0.f};
        #pragma unroll
        for (int ni = 0; ni < 4; ++ni)
            #pragma unroll
            for (int b = 0; b < 4; ++b)
                part[b] += fast_tanh(acc[mi][ni][b]) * onev[ni];
        #pragma unroll
        for (int off = 1; off < 16; off <<= 1)
            #pragma unroll
            for (int b = 0; b < 4; ++b)
                part[b] += __shfl_xor(part[b], off, 64);
        #pragma unroll
        for (int b = 0; b < 4; ++b)
            if (l15 == mi * 4 + b)
                atomicAdd(&logits[m0 + wr * 64 + mi * 16 + l4 * 4 + b], part[b]);
    }
}

// ---------------- softmax over T per batch ----------------
__global__ __launch_bounds__(256)
void softmax_kernel(const float* __restrict__ logits, float* __restrict__ att) {
    int b = blockIdx.x, tid = threadIdx.x;
    const float* lr = logits + (b << 11);
    float lv[8];
    float mx = -1e30f;
    #pragma unroll
    for (int i = 0; i < 8; ++i) { lv[i] = lr[tid + (i << 8)]; mx = fmaxf(mx, lv[i]); }
    #pragma unroll
    for (int off = 1; off < 64; off <<= 1) mx = fmaxf(mx, __shfl_xor(mx, off, 64));
    __shared__ float redm[4];
    __shared__ float reds[4];
    int wv = tid >> 6;
    if ((tid & 63) == 0) redm[wv] = mx;
    __syncthreads();
    mx = fmaxf(fmaxf(redm[0], redm[1]), fmaxf(redm[2], redm[3]));
    float s = 0.f;
    #pragma unroll
    for (int i = 0; i < 8; ++i) { lv[i] = expf(lv[i] - mx); s += lv[i]; }
    #pragma unroll
    for (int off = 1; off < 64; off <<= 1) s += __shfl_xor(s, off, 64);
    if ((tid & 63) == 0) reds[wv] = s;
    __syncthreads();
    s = reds[0] + reds[1] + reds[2] + reds[3];
    float inv = 1.0f / (s + 1e-7f);
    #pragma unroll
    for (int i = 0; i < 8; ++i) att[(b << 11) + tid + (i << 8)] = lv[i] * inv;
}

// ------- result[b][d] = sum_t many[b][t][d] * att[b][t] (fp16 input) -------
__global__ __launch_bounds__(256)
void out_kernel_h(const _Float16* __restrict__ manyh, const float* __restrict__ att,
                  float* __restrict__ out) {
    int b = blockIdx.x >> 4, tch = blockIdx.x & 15;
    int tid = threadIdx.x;
    __shared__ float aw[128];
    if (tid < 128) aw[tid] = att[(b << 11) + tch * 128 + tid];
    __syncthreads();
    const _Float16* mp = manyh + (((size_t)b * NT + tch * 128) << 10) + tid * 4;
    float a0 = 0.f, a1 = 0.f, a2 = 0.f, a3 = 0.f;
    for (int t = 0; t < 128; ++t) {
        float wgt = aw[t];
        union { _Float16 h[4]; uint2 u; } v;
        v.u = *reinterpret_cast<const uint2*>(mp + ((size_t)t << 10));
        a0 = fmaf((float)v.h[0], wgt, a0); a1 = fmaf((float)v.h[1], wgt, a1);
        a2 = fmaf((float)v.h[2], wgt, a2); a3 = fmaf((float)v.h[3], wgt, a3);
    }
    float* op = out + (b << 10) + tid * 4;
    atomicAdd(op + 0, a0); atomicAdd(op + 1, a1);
    atomicAdd(op + 2, a2); atomicAdd(op + 3, a3);
}

// ---------------- fallback out (f32 many) ----------------
__global__ __launch_bounds__(256)
void out_kernel(const float* __restrict__ many, const float* __restrict__ att,
                float* __restrict__ out) {
    int b = blockIdx.x >> 4, tch = blockIdx.x & 15;
    int tid = threadIdx.x;
    __shared__ float aw[128];
    if (tid < 128) aw[tid] = att[(b << 11) + tch * 128 + tid];
    __syncthreads();
    const float* mp = many + (((size_t)b * NT + tch * 128) << 10) + tid * 4;
    float ax = 0.f, ay = 0.f, az = 0.f, aww = 0.f;
    for (int t = 0; t < 128; ++t) {
        float wgt = aw[t];
        float4 v = *reinterpret_cast<const float4*>(mp + ((size_t)t << 10));
        ax = fmaf(v.x, wgt, ax); ay = fmaf(v.y, wgt, ay);
        az = fmaf(v.z, wgt, az); aww = fmaf(v.w, wgt, aww);
    }
    float* op = out + (b << 10) + tid * 4;
    atomicAdd(op + 0, ax); atomicAdd(op + 1, ay);
    atomicAdd(op + 2, az); atomicAdd(op + 3, aww);
}

extern "C" void kernel_launch(void* const* d_in, const int* in_sizes, int n_in,
                              void* d_out, int out_size, void* d_ws, size_t ws_size,
                              hipStream_t stream) {
    const float* one  = (const float*)d_in[0];   // [32][1024]
    const float* many = (const float*)d_in[1];   // [32][2048][1024]
    const float* W    = (const float*)d_in[2];   // [1024][1024]
    float* out = (float*)d_out;                  // [0,32768) result | [32768,98304) att

    size_t wtB = (size_t)ND * ND * 2;            // 2 MB
    size_t lgB = (size_t)NM * 4;                 // 256 KB
    size_t mhB = (size_t)NM * ND * 2;            // 128 MB
    _Float16* Wt    = (_Float16*)d_ws;
    float*    logits = (float*)((char*)d_ws + wtB);
    _Float16* manyh = (_Float16*)((char*)d_ws + wtB + lgB);
    float*    att   = out + NB * ND;
    bool big = ws_size >= wtB + lgB + mhB;       // harness constant -> deterministic

    (void)hipMemsetAsync(out, 0, (size_t)NB * ND * sizeof(float), stream);
    (void)hipMemsetAsync(logits, 0, (size_t)NM * sizeof(float), stream);

    wt_kernel<<<dim3(32, 32), dim3(32, 8), 0, stream>>>(W, Wt);
    if (big) {
        conv_kernel<<<2048, 256, 0, stream>>>(many, manyh);
        gemm_logits_8p<<<1024, 512, 0, stream>>>(manyh, Wt, one, logits);
    } else {
        gemm_logits<<<4096, 256, 0, stream>>>(many, Wt, one, logits);
    }
    softmax_kernel<<<NB, 256, 0, stream>>>(logits, att);
    if (big) out_kernel_h<<<NB * 16, 256, 0, stream>>>(manyh, att, out);
    else     out_kernel<<<NB * 16, 256, 0, stream>>>(many, att, out);
}

// Round 6
// 272.808 us; speedup vs baseline: 1.0247x; 1.0247x over previous
//
#include <hip/hip_runtime.h>
#include <hip/hip_bf16.h>

typedef _Float16 half8v __attribute__((ext_vector_type(8)));
typedef __fp16  fp16x2 __attribute__((ext_vector_type(2)));   // cvt_pkrtz return type
typedef float floatx4 __attribute__((ext_vector_type(4)));

#define NB 32
#define NT 2048
#define ND 1024
#define NM (NB * NT)

// global->LDS direct DMA, 16B per lane. Linear LDS dest; swizzle on the
// GLOBAL source address (rule #21).
#define GL16(g, l)                                                             \
    __builtin_amdgcn_global_load_lds(                                          \
        (const __attribute__((address_space(1))) void*)(g),                    \
        (__attribute__((address_space(3))) void*)(l), 16, 0, 0)

__device__ __forceinline__ float fast_tanh(float x) {
    x = fminf(9.0f, fmaxf(-9.0f, x));
    float e = __builtin_amdgcn_exp2f(x * 2.8853900817779268f); // e^(2x)
    return (e - 1.0f) * __builtin_amdgcn_rcpf(e + 1.0f);
}

// ---------------- W [K][N] f32  ->  Wt [N][K] fp16 ----------------
__global__ __launch_bounds__(256)
void wt_kernel(const float* __restrict__ W, _Float16* __restrict__ Wt) {
    __shared__ float tile[32][33];
    int tx = threadIdx.x, ty = threadIdx.y;
    int bx = blockIdx.x, by = blockIdx.y;
    #pragma unroll
    for (int i = 0; i < 4; ++i) {
        int y = by * 32 + ty + i * 8;
        tile[ty + i * 8][tx] = W[y * ND + bx * 32 + tx];
    }
    __syncthreads();
    #pragma unroll
    for (int i = 0; i < 4; ++i) {
        int e = bx * 32 + ty + i * 8;
        Wt[e * ND + by * 32 + tx] = (_Float16)tile[tx][ty + i * 8];
    }
}

// ---------------- many f32 -> manyh fp16 (streaming, RTN) ----------------
__global__ __launch_bounds__(256)
void conv_kernel(const float* __restrict__ many, _Float16* __restrict__ manyh) {
    size_t idx = ((size_t)blockIdx.x * 256 + threadIdx.x) * 8;
    size_t stride = (size_t)gridDim.x * 256 * 8;
    for (size_t i = idx; i < (size_t)NM * ND; i += stride) {
        float4 a = *reinterpret_cast<const float4*>(many + i);
        float4 b = *reinterpret_cast<const float4*>(many + i + 4);
        union { _Float16 h[8]; uint4 u; } o;
        o.h[0] = (_Float16)a.x; o.h[1] = (_Float16)a.y;
        o.h[2] = (_Float16)a.z; o.h[3] = (_Float16)a.w;
        o.h[4] = (_Float16)b.x; o.h[5] = (_Float16)b.y;
        o.h[6] = (_Float16)b.z; o.h[7] = (_Float16)b.w;
        *reinterpret_cast<uint4*>(manyh + i) = o.u;
    }
}

// ---- m201-faithful 4-phase GEMM + tanh + dot(one) -> logits (fp16) --------
// BM=BN=256, BK=64, 512 thr (8 waves, 2M x 4N, wave-out 128x64).
// LDS 128 KiB = 2 dbuf x { A: 2 half x 16K | B: 2 half x 16K }.
// Staging unit = one 64-row load (8 KB) of a half; stagger:
//   phase (t,0): A(t+1)L2s   (t,1): B0(t+1)   (t,2): B1(t+1)   (t,3): A(t+2)L1s
// Single counted vmcnt(2) per K-tile (never 0 until the tail).
__global__ __launch_bounds__(512, 2)
void gemm_logits_8p(const _Float16* __restrict__ manyh, const _Float16* __restrict__ Wt,
                    const float* __restrict__ one, float* __restrict__ logits) {
    __shared__ uint4 LDSQ[8192];          // 128 KiB
    char* Ld = (char*)LDSQ;

    int bid = blockIdx.x;                  // 1024 blocks
    int j = (bid & 7) * 128 + (bid >> 3);  // XCD-chunked, bijective (1024%8==0)
    int mb = j >> 2, nb = j & 3;
    int m0 = mb * 256, n0 = nb * 256;

    int tid = threadIdx.x;
    int lane = tid & 63, w = tid >> 6;
    int wr = w >> 2, wc = w & 3;           // 2 M-halves x 4 N-quarters
    int l15 = lane & 15, l4 = lane >> 4;

    // staging: thread -> row tid>>3 (0..63), chunk tid&7; src chunk ^= row&7
    const char* aS = (const char*)manyh + ((size_t)(m0 + (tid >> 3)) << 11)
                   + (size_t)(((tid & 7) ^ ((tid >> 3) & 7)) << 4);
    const char* bS = (const char*)Wt + ((size_t)(n0 + (tid >> 3)) << 11)
                   + (size_t)(((tid & 7) ^ ((tid >> 3) & 7)) << 4);
    int ldst = tid * 16;

    // one unit-load: OP 0=A/1=B, half H, load L (rows L*64..L*64+63), tile TT
#define SU(OP, H, L, TT)                                                        \
    GL16(((OP) ? bS : aS) + (((size_t)((H) * 128 + (L) * 64)) << 11) + (TT) * 128, \
         Ld + (((TT) & 1) << 16) + ((OP) << 15) + ((H) << 14) + ((L) << 13) + ldst)

    floatx4 acc[8][4] = {};
    // lane-constant frag offsets within a row-block: row l15, chunk (kk*4+l4)^key
    int key = l15 & 7;
    int lofA0 = l15 * 128 + (((0 | l4) ^ key) << 4);   // kk=0
    int lofA1 = l15 * 128 + (((4 | l4) ^ key) << 4);   // kk=1

    // ---- prologue: tile0 complete + A(1)L1s; allow last 2 outstanding ----
    SU(0, 0, 0, 0); SU(0, 1, 0, 0);    // A(0) L1s
    SU(0, 0, 1, 0); SU(0, 1, 1, 0);    // A(0) L2s
    SU(1, 0, 0, 0); SU(1, 0, 1, 0);    // B0(0)
    SU(1, 1, 0, 0); SU(1, 1, 1, 0);    // B1(0)
    SU(0, 0, 0, 1); SU(0, 1, 0, 1);    // A(1) L1s
    asm volatile("s_waitcnt vmcnt(2)" ::: "memory");
    __builtin_amdgcn_sched_barrier(0);
    __builtin_amdgcn_s_barrier();

    #pragma unroll 1
    for (int t = 0; t < 16; ++t) {
        const char* ab = Ld + ((t & 1) << 16) + (wr << 14);
        const char* bb = Ld + ((t & 1) << 16) + 32768 + ((wc >> 1) << 14)
                       + ((wc & 1) << 13);
        half8v bf0[4], bf1[4];
        #pragma unroll
        for (int p = 0; p < 4; ++p) {
            // frag reads: quadrant p = rows [p*32, p*32+32) of this wave's half
            int rb = (p * 32) << 7;
            half8v a0k0 = *(const half8v*)(ab + rb + lofA0);
            half8v a0k1 = *(const half8v*)(ab + rb + lofA1);
            half8v a1k0 = *(const half8v*)(ab + rb + (16 << 7) + lofA0);
            half8v a1k1 = *(const half8v*)(ab + rb + (16 << 7) + lofA1);
            if (p == 0) {
                #pragma unroll
                for (int ni = 0; ni < 4; ++ni) {
                    bf0[ni] = *(const half8v*)(bb + ((ni * 16) << 7) + lofA0);
                    bf1[ni] = *(const half8v*)(bb + ((ni * 16) << 7) + lofA1);
                }
            }
            // staggered staging (see header comment)
            if (t < 15) {
                if (p == 0)      { SU(0, 0, 1, t + 1); SU(0, 1, 1, t + 1); }
                else if (p == 1) { SU(1, 0, 0, t + 1); SU(1, 0, 1, t + 1); }
                else if (p == 2) { SU(1, 1, 0, t + 1); SU(1, 1, 1, t + 1); }
                else if (t < 14) { SU(0, 0, 0, t + 2); SU(0, 1, 0, t + 2); }
            }
            __builtin_amdgcn_s_barrier();
            __builtin_amdgcn_s_setprio(1);
            #pragma unroll
            for (int ni = 0; ni < 4; ++ni) {
                acc[2 * p][ni] = __builtin_amdgcn_mfma_f32_16x16x32_f16(
                    a0k0, bf0[ni], acc[2 * p][ni], 0, 0, 0);
                acc[2 * p][ni] = __builtin_amdgcn_mfma_f32_16x16x32_f16(
                    a0k1, bf1[ni], acc[2 * p][ni], 0, 0, 0);
                acc[2 * p + 1][ni] = __builtin_amdgcn_mfma_f32_16x16x32_f16(
                    a1k0, bf0[ni], acc[2 * p + 1][ni], 0, 0, 0);
                acc[2 * p + 1][ni] = __builtin_amdgcn_mfma_f32_16x16x32_f16(
                    a1k1, bf1[ni], acc[2 * p + 1][ni], 0, 0, 0);
            }
            __builtin_amdgcn_s_setprio(0);
            if (p == 3) {
                if (t < 14)       asm volatile("s_waitcnt vmcnt(2)" ::: "memory");
                else if (t == 14) asm volatile("s_waitcnt vmcnt(0)" ::: "memory");
                __builtin_amdgcn_sched_barrier(0);
            }
            __builtin_amdgcn_s_barrier();
        }
    }
#undef SU

    // epilogue: tanh * one, reduce over 16 col-lanes, atomicAdd logits
    int bidx = m0 >> 11;
    float onev[4];
    #pragma unroll
    for (int ni = 0; ni < 4; ++ni)
        onev[ni] = one[(bidx << 10) + n0 + wc * 64 + ni * 16 + l15];

    #pragma unroll
    for (int mi = 0; mi < 8; ++mi) {
        float part[4] = {0.f, 0.f, 0.f, 0.f};
        #pragma unroll
        for (int ni = 0; ni < 4; ++ni)
            #pragma unroll
            for (int b = 0; b < 4; ++b)
                part[b] += fast_tanh(acc[mi][ni][b]) * onev[ni];
        #pragma unroll
        for (int off = 1; off < 16; off <<= 1)
            #pragma unroll
            for (int b = 0; b < 4; ++b)
                part[b] += __shfl_xor(part[b], off, 64);
        #pragma unroll
        for (int b = 0; b < 4; ++b)
            if (l15 == ((mi * 4 + b) & 15))
                atomicAdd(&logits[m0 + wr * 128 + mi * 16 + l4 * 4 + b], part[b]);
    }
}

// ---------------- fallback GEMM (A f32 from global, cvt at frag read) ------
__global__ __launch_bounds__(256, 2)
void gemm_logits(const float* __restrict__ many, const _Float16* __restrict__ Wt,
                 const float* __restrict__ one, float* __restrict__ logits) {
    __shared__ uint4 AsQ[2048];
    __shared__ uint4 BsQ[1024];
    char* AsB = (char*)AsQ;
    char* BsB = (char*)BsQ;

    int bid = blockIdx.x;
    int j = (bid & 7) * 512 + (bid >> 3);
    int mb = j >> 3, nb = j & 7;
    int m0 = mb * 128, n0 = nb * 128;

    int tid = threadIdx.x;
    int lane = tid & 63, w = tid >> 6;
    int wr = w >> 1, wc = w & 1;
    int l15 = lane & 15, l4 = lane >> 4;

    const char* aS = (const char*)many + ((size_t)(m0 + (tid >> 4)) << 12)
        + (size_t)(((tid & 15) ^ ((tid >> 4) & 7)) << 4);
    const char* bS = (const char*)Wt + ((size_t)(n0 + (tid >> 3)) << 11)
        + (size_t)(((tid & 7) ^ ((tid >> 3) & 7)) << 4);
    char* aD = AsB + tid * 16;
    char* bD = BsB + tid * 16;

    floatx4 acc[4][4] = {};

    for (int kb = 0; kb < 1024; kb += 64) {
        #pragma unroll
        for (int i = 0; i < 8; ++i)
            GL16(aS + kb * 4 + i * 65536, aD + i * 4096);
        #pragma unroll
        for (int i = 0; i < 4; ++i)
            GL16(bS + kb * 2 + i * 65536, bD + i * 4096);
        __syncthreads();

        #pragma unroll
        for (int ks = 0; ks < 64; ks += 32) {
            half8v af[4], bf[4];
            #pragma unroll
            for (int mi = 0; mi < 4; ++mi) {
                int r = wr * 64 + mi * 16 + l15;
                int s = l15 & 7;
                const char* base = AsB + r * 256;
                int c0 = (ks >> 2) + l4 * 2;
                float4 x = *(const float4*)(base + (size_t)((c0 ^ s) << 4));
                float4 y = *(const float4*)(base + (size_t)(((c0 + 1) ^ s) << 4));
                union { fp16x2 p[4]; half8v h; } u;
                u.p[0] = __builtin_amdgcn_cvt_pkrtz(x.x, x.y);
                u.p[1] = __builtin_amdgcn_cvt_pkrtz(x.z, x.w);
                u.p[2] = __builtin_amdgcn_cvt_pkrtz(y.x, y.y);
                u.p[3] = __builtin_amdgcn_cvt_pkrtz(y.z, y.w);
                af[mi] = u.h;
            }
            #pragma unroll
            for (int ni = 0; ni < 4; ++ni) {
                int r = wc * 64 + ni * 16 + l15;
                int s = l15 & 7;
                int c = (ks >> 3) + l4;
                bf[ni] = *(const half8v*)(BsB + r * 128 + (size_t)((c ^ s) << 4));
            }
            #pragma unroll
            for (int mi = 0; mi < 4; ++mi)
                #pragma unroll
                for (int ni = 0; ni < 4; ++ni)
                    acc[mi][ni] = __builtin_amdgcn_mfma_f32_16x16x32_f16(
                        af[mi], bf[ni], acc[mi][ni], 0, 0, 0);
        }
        __syncthreads();
    }

    int bidx = m0 >> 11;
    float onev[4];
    #pragma unroll
    for (int ni = 0; ni < 4; ++ni)
        onev[ni] = one[(bidx << 10) + n0 + wc * 64 + ni * 16 + l15];

    #pragma unroll
    for (int mi = 0; mi < 4; ++mi) {
        float part[4] = {0.f, 0.f, 0.f, 0.f};
        #pragma unroll
        for (int ni = 0; ni < 4; ++ni)
            #pragma unroll
            for (int b = 0; b < 4; ++b)
                part[b] += fast_tanh(acc[mi][ni][b]) * onev[ni];
        #pragma unroll
        for (int off = 1; off < 16; off <<= 1)
            #pragma unroll
            for (int b = 0; b < 4; ++b)
                part[b] += __shfl_xor(part[b], off, 64);
        #pragma unroll
        for (int b = 0; b < 4; ++b)
            if (l15 == mi * 4 + b)
                atomicAdd(&logits[m0 + wr * 64 + mi * 16 + l4 * 4 + b], part[b]);
    }
}

// ---------------- softmax over T per batch ----------------
__global__ __launch_bounds__(256)
void softmax_kernel(const float* __restrict__ logits, float* __restrict__ att) {
    int b = blockIdx.x, tid = threadIdx.x;
    const float* lr = logits + (b << 11);
    float lv[8];
    float mx = -1e30f;
    #pragma unroll
    for (int i = 0; i < 8; ++i) { lv[i] = lr[tid + (i << 8)]; mx = fmaxf(mx, lv[i]); }
    #pragma unroll
    for (int off = 1; off < 64; off <<= 1) mx = fmaxf(mx, __shfl_xor(mx, off, 64));
    __shared__ float redm[4];
    __shared__ float reds[4];
    int wv = tid >> 6;
    if ((tid & 63) == 0) redm[wv] = mx;
    __syncthreads();
    mx = fmaxf(fmaxf(redm[0], redm[1]), fmaxf(redm[2], redm[3]));
    float s = 0.f;
    #pragma unroll
    for (int i = 0; i < 8; ++i) { lv[i] = expf(lv[i] - mx); s += lv[i]; }
    #pragma unroll
    for (int off = 1; off < 64; off <<= 1) s += __shfl_xor(s, off, 64);
    if ((tid & 63) == 0) reds[wv] = s;
    __syncthreads();
    s = reds[0] + reds[1] + reds[2] + reds[3];
    float inv = 1.0f / (s + 1e-7f);
    #pragma unroll
    for (int i = 0; i < 8; ++i) att[(b << 11) + tid + (i << 8)] = lv[i] * inv;
}

// ------- result[b][d] = sum_t many[b][t][d] * att[b][t] (fp16 input) -------
__global__ __launch_bounds__(256)
void out_kernel_h(const _Float16* __restrict__ manyh, const float* __restrict__ att,
                  float* __restrict__ out) {
    int b = blockIdx.x >> 4, tch = blockIdx.x & 15;
    int tid = threadIdx.x;
    __shared__ float aw[128];
    if (tid < 128) aw[tid] = att[(b << 11) + tch * 128 + tid];
    __syncthreads();
    const _Float16* mp = manyh + (((size_t)b * NT + tch * 128) << 10) + tid * 4;
    float a0 = 0.f, a1 = 0.f, a2 = 0.f, a3 = 0.f;
    for (int t = 0; t < 128; ++t) {
        float wgt = aw[t];
        union { _Float16 h[4]; uint2 u; } v;
        v.u = *reinterpret_cast<const uint2*>(mp + ((size_t)t << 10));
        a0 = fmaf((float)v.h[0], wgt, a0); a1 = fmaf((float)v.h[1], wgt, a1);
        a2 = fmaf((float)v.h[2], wgt, a2); a3 = fmaf((float)v.h[3], wgt, a3);
    }
    float* op = out + (b << 10) + tid * 4;
    atomicAdd(op + 0, a0); atomicAdd(op + 1, a1);
    atomicAdd(op + 2, a2); atomicAdd(op + 3, a3);
}

// ---------------- fallback out (f32 many) ----------------
__global__ __launch_bounds__(256)
void out_kernel(const float* __restrict__ many, const float* __restrict__ att,
                float* __restrict__ out) {
    int b = blockIdx.x >> 4, tch = blockIdx.x & 15;
    int tid = threadIdx.x;
    __shared__ float aw[128];
    if (tid < 128) aw[tid] = att[(b << 11) + tch * 128 + tid];
    __syncthreads();
    const float* mp = many + (((size_t)b * NT + tch * 128) << 10) + tid * 4;
    float ax = 0.f, ay = 0.f, az = 0.f, aww = 0.f;
    for (int t = 0; t < 128; ++t) {
        float wgt = aw[t];
        float4 v = *reinterpret_cast<const float4*>(mp + ((size_t)t << 10));
        ax = fmaf(v.x, wgt, ax); ay = fmaf(v.y, wgt, ay);
        az = fmaf(v.z, wgt, az); aww = fmaf(v.w, wgt, aww);
    }
    float* op = out + (b << 10) + tid * 4;
    atomicAdd(op + 0, ax); atomicAdd(op + 1, ay);
    atomicAdd(op + 2, az); atomicAdd(op + 3, aww);
}

extern "C" void kernel_launch(void* const* d_in, const int* in_sizes, int n_in,
                              void* d_out, int out_size, void* d_ws, size_t ws_size,
                              hipStream_t stream) {
    const float* one  = (const float*)d_in[0];   // [32][1024]
    const float* many = (const float*)d_in[1];   // [32][2048][1024]
    const float* W    = (const float*)d_in[2];   // [1024][1024]
    float* out = (float*)d_out;                  // [0,32768) result | [32768,98304) att

    size_t wtB = (size_t)ND * ND * 2;            // 2 MB
    size_t lgB = (size_t)NM * 4;                 // 256 KB
    size_t mhB = (size_t)NM * ND * 2;            // 128 MB
    _Float16* Wt    = (_Float16*)d_ws;
    float*    logits = (float*)((char*)d_ws + wtB);
    _Float16* manyh = (_Float16*)((char*)d_ws + wtB + lgB);
    float*    att   = out + NB * ND;
    bool big = ws_size >= wtB + lgB + mhB;       // harness constant -> deterministic

    (void)hipMemsetAsync(out, 0, (size_t)NB * ND * sizeof(float), stream);
    (void)hipMemsetAsync(logits, 0, (size_t)NM * sizeof(float), stream);

    wt_kernel<<<dim3(32, 32), dim3(32, 8), 0, stream>>>(W, Wt);
    if (big) {
        conv_kernel<<<2048, 256, 0, stream>>>(many, manyh);
        gemm_logits_8p<<<1024, 512, 0, stream>>>(manyh, Wt, one, logits);
    } else {
        gemm_logits<<<4096, 256, 0, stream>>>(many, Wt, one, logits);
    }
    softmax_kernel<<<NB, 256, 0, stream>>>(logits, att);
    if (big) out_kernel_h<<<NB * 16, 256, 0, stream>>>(manyh, att, out);
    else     out_kernel<<<NB * 16, 256, 0, stream>>>(many, att, out);
}